// Round 5
// baseline (2818.480 us; speedup 1.0000x reference)
//
#include <hip/hip_runtime.h>
#include <hip/hip_bf16.h>

#define D 128          // D_IN == D_OUT == 128
#define GEMM_ROWS 64   // rows per block in the dense GEMM
#define BROWS 128      // nodes per bucket (LDS accum = 128*128*4 = 64 KB)
#define BSHIFT 7       // log2(BROWS)
#define BIN_CHUNK 4096 // edges per binning block

static __device__ inline unsigned short f2bf(float x) {
    unsigned int u = __float_as_uint(x);
    return (unsigned short)((u + 0x7FFFu + ((u >> 16) & 1u)) >> 16);  // RNE
}
static __device__ inline float bf2f(unsigned int h16) {
    return __uint_as_float(h16 << 16);
}

// ---------------------------------------------------------------------------
// S = X @ W  (fp32 vector GEMM; no fp32 MFMA on CDNA4). Output fp32 or bf16.
// W (64KB) + 64-row X tile (stride 132) in LDS; 4x8 register tile per thread.
// ---------------------------------------------------------------------------
template <bool BF16OUT>
__global__ __launch_bounds__(256) void gemm_kernel(const float* __restrict__ X,
                                                   const float* __restrict__ W,
                                                   void* __restrict__ Sout,
                                                   int n_rows) {
    __shared__ float Ws[D * D];
    __shared__ float Xs[GEMM_ROWS * 132];

    const int tid  = threadIdx.x;
    const int row0 = blockIdx.x * GEMM_ROWS;

    #pragma unroll
    for (int i = 0; i < 16; ++i) {
        int idx = tid + i * 256;
        ((float4*)Ws)[idx] = ((const float4*)W)[idx];
    }
    #pragma unroll
    for (int i = 0; i < 8; ++i) {
        int idx = tid + i * 256;
        int r = idx >> 5, c4 = idx & 31;
        if (row0 + r < n_rows) {
            float4 v = ((const float4*)(X + (size_t)(row0 + r) * D))[c4];
            *((float4*)&Xs[r * 132 + c4 * 4]) = v;
        }
    }
    __syncthreads();

    const int cg = tid & 15, rg = tid >> 4;
    const int r0 = rg * 4;
    const int c0 = cg * 4;
    const int c1 = 64 + cg * 4;

    float acc[4][8];
    #pragma unroll
    for (int r = 0; r < 4; ++r)
        #pragma unroll
        for (int c = 0; c < 8; ++c) acc[r][c] = 0.f;

    #pragma unroll 4
    for (int k = 0; k < D; ++k) {
        float4 w0 = *((const float4*)&Ws[k * D + c0]);
        float4 w1 = *((const float4*)&Ws[k * D + c1]);
        #pragma unroll
        for (int r = 0; r < 4; ++r) {
            float x = Xs[(r0 + r) * 132 + k];
            acc[r][0] += x * w0.x; acc[r][1] += x * w0.y;
            acc[r][2] += x * w0.z; acc[r][3] += x * w0.w;
            acc[r][4] += x * w1.x; acc[r][5] += x * w1.y;
            acc[r][6] += x * w1.z; acc[r][7] += x * w1.w;
        }
    }

    #pragma unroll
    for (int r = 0; r < 4; ++r) {
        int row = row0 + r0 + r;
        if (row < n_rows) {
            if constexpr (BF16OUT) {
                unsigned short* Sb = (unsigned short*)Sout;
                uint2 v0, v1;
                v0.x = (unsigned)f2bf(acc[r][0]) | ((unsigned)f2bf(acc[r][1]) << 16);
                v0.y = (unsigned)f2bf(acc[r][2]) | ((unsigned)f2bf(acc[r][3]) << 16);
                v1.x = (unsigned)f2bf(acc[r][4]) | ((unsigned)f2bf(acc[r][5]) << 16);
                v1.y = (unsigned)f2bf(acc[r][6]) | ((unsigned)f2bf(acc[r][7]) << 16);
                ((uint2*)(Sb + (size_t)row * D))[cg]      = v0;
                ((uint2*)(Sb + (size_t)row * D))[16 + cg] = v1;
            } else {
                float* S = (float*)Sout;
                float4 o0 = {acc[r][0], acc[r][1], acc[r][2], acc[r][3]};
                float4 o1 = {acc[r][4], acc[r][5], acc[r][6], acc[r][7]};
                ((float4*)(S + (size_t)row * D))[cg]      = o0;
                ((float4*)(S + (size_t)row * D))[16 + cg] = o1;
            }
        }
    }
}

// ---------------------------------------------------------------------------
// Coarse bucket histogram: LDS-aggregated, then one global atomic per bucket.
// ---------------------------------------------------------------------------
__global__ __launch_bounds__(256) void bhist_kernel(const int* __restrict__ erow,
                                                    int* __restrict__ cnt,
                                                    int n_edges, int nb) {
    __shared__ int h[1024];
    for (int i = threadIdx.x; i < nb; i += 256) h[i] = 0;
    __syncthreads();
    int i = blockIdx.x * blockDim.x + threadIdx.x;
    int stride = gridDim.x * blockDim.x;
    for (; i < n_edges; i += stride) atomicAdd(&h[erow[i] >> BSHIFT], 1);
    __syncthreads();
    for (int b = threadIdx.x; b < nb; b += 256)
        if (h[b]) atomicAdd(&cnt[b], h[b]);
}

// single block: exclusive scan of cnt[0..nb) -> cur (bucket start cursors)
__global__ __launch_bounds__(1024) void bscan_kernel(const int* __restrict__ cnt,
                                                     int* __restrict__ cur, int nb) {
    __shared__ int s[1024];
    int tid = threadIdx.x;
    int v = (tid < nb) ? cnt[tid] : 0;
    s[tid] = v;
    __syncthreads();
    for (int d = 1; d < 1024; d <<= 1) {
        int t = (tid >= d) ? s[tid - d] : 0;
        __syncthreads();
        s[tid] += t;
        __syncthreads();
    }
    if (tid < nb) cur[tid] = s[tid] - v;   // exclusive
}

// ---------------------------------------------------------------------------
// Binning: each block takes a BIN_CHUNK of edges, reserves a contiguous range
// per touched bucket (one global atomic per (block,bucket)), then writes its
// edges densely into those ranges -> temporally-clustered line writes.
// Packed edge: x = (localrow<<25) | col, y = weight bits.
// After this kernel, cur[b] == end-of-bucket-b (segments are contiguous).
// ---------------------------------------------------------------------------
__global__ __launch_bounds__(256) void bin_kernel(const int* __restrict__ erow,
                                                  const int* __restrict__ ecol,
                                                  const float* __restrict__ ew,
                                                  int* __restrict__ cur,
                                                  int2* __restrict__ binned,
                                                  int n_edges, int nb) {
    __shared__ int h[1024];
    __shared__ int base[1024];
    const int c0 = blockIdx.x * BIN_CHUNK;
    for (int i = threadIdx.x; i < nb; i += 256) h[i] = 0;
    __syncthreads();
    for (int k = 0; k < BIN_CHUNK; k += 256) {
        int e = c0 + k + threadIdx.x;
        if (e < n_edges) atomicAdd(&h[erow[e] >> BSHIFT], 1);
    }
    __syncthreads();
    for (int b = threadIdx.x; b < nb; b += 256) {
        int c = h[b];
        if (c) base[b] = atomicAdd(&cur[b], c);
        h[b] = 0;   // reuse as local cursor
    }
    __syncthreads();
    for (int k = 0; k < BIN_CHUNK; k += 256) {
        int e = c0 + k + threadIdx.x;
        if (e < n_edges) {
            int row = erow[e];
            int b = row >> BSHIFT;
            int pos = base[b] + atomicAdd(&h[b], 1);
            int2 p;
            p.x = (int)(((unsigned)(row & (BROWS - 1)) << 25) | (unsigned)ecol[e]);
            p.y = __float_as_int(ew[e]);
            binned[pos] = p;
        }
    }
}

// ---------------------------------------------------------------------------
// Bucket SpMM: one block per bucket of 128 rows, 128x128 fp32 accumulator in
// LDS. Edges stream coalesced; lane l owns cols 2l,2l+1 (4B bf16x2 gather +
// 2 LDS float atomics, 2-way bank aliasing = free). Out written exactly once.
// ---------------------------------------------------------------------------
__global__ __launch_bounds__(512) void spmm_bucket_kernel(const unsigned short* __restrict__ Sb,
                                                          const int* __restrict__ cur_end,
                                                          const int2* __restrict__ binned,
                                                          const float* __restrict__ bias,
                                                          float* __restrict__ out,
                                                          int n_nodes) {
    __shared__ float acc[BROWS * D];   // 64 KB

    const int b     = blockIdx.x;
    const int row0  = b * BROWS;
    const int nrows = min(BROWS, n_nodes - row0);

    for (int i = threadIdx.x; i < BROWS * D / 4; i += 512)
        ((float4*)acc)[i] = make_float4(0.f, 0.f, 0.f, 0.f);
    __syncthreads();

    const int end   = cur_end[b];
    const int start = b ? cur_end[b - 1] : 0;
    const int wid   = threadIdx.x >> 6;
    const int lane  = threadIdx.x & 63;
    const int cnt   = end - start;
    const int per   = (cnt + 7) >> 3;
    const int es    = start + wid * per;
    const int ee    = min(es + per, end);

    int e = es;
    for (; e + 3 < ee; e += 4) {
        int2 p[4];
        #pragma unroll
        for (int j = 0; j < 4; ++j) p[j] = binned[e + j];
        unsigned sv[4];
        #pragma unroll
        for (int j = 0; j < 4; ++j) {
            unsigned col = (unsigned)p[j].x & 0x1FFFFFFu;
            sv[j] = ((const unsigned*)(Sb + (size_t)col * D))[lane];
        }
        #pragma unroll
        for (int j = 0; j < 4; ++j) {
            unsigned lr = (unsigned)p[j].x >> 25;
            float w = __int_as_float(p[j].y);
            atomicAdd(&acc[lr * D + lane * 2],     w * bf2f(sv[j] & 0xFFFFu));
            atomicAdd(&acc[lr * D + lane * 2 + 1], w * bf2f(sv[j] >> 16));
        }
    }
    for (; e < ee; ++e) {
        int2 p = binned[e];
        unsigned col = (unsigned)p.x & 0x1FFFFFFu;
        unsigned lr  = (unsigned)p.x >> 25;
        float w = __int_as_float(p.y);
        unsigned sv = ((const unsigned*)(Sb + (size_t)col * D))[lane];
        atomicAdd(&acc[lr * D + lane * 2],     w * bf2f(sv & 0xFFFFu));
        atomicAdd(&acc[lr * D + lane * 2 + 1], w * bf2f(sv >> 16));
    }
    __syncthreads();

    for (int i = threadIdx.x; i < nrows * (D / 4); i += 512) {
        float4 a  = ((float4*)acc)[i];
        float4 bb = ((const float4*)bias)[i & 31];
        a.x += bb.x; a.y += bb.y; a.z += bb.z; a.w += bb.w;
        ((float4*)(out + (size_t)row0 * D))[i] = a;
    }
}

// ---------------------------------------------------------------------------
// Fallback path (ws too small / too many buckets): fp32 S + output atomics.
// ---------------------------------------------------------------------------
__global__ __launch_bounds__(256) void init_out_kernel(float* __restrict__ out,
                                                       const float* __restrict__ bias,
                                                       int total4) {
    int idx = blockIdx.x * blockDim.x + threadIdx.x;
    int stride = gridDim.x * blockDim.x;
    for (; idx < total4; idx += stride) {
        float4 b = ((const float4*)bias)[idx & 31];
        ((float4*)out)[idx] = b;
    }
}

__global__ __launch_bounds__(256) void spmm_atomic_kernel(const float* __restrict__ S,
                                                          const int* __restrict__ erow,
                                                          const int* __restrict__ ecol,
                                                          const float* __restrict__ ew,
                                                          float* __restrict__ out,
                                                          int n_edges) {
    const int lane   = threadIdx.x & 63;
    const int wave   = blockIdx.x * (blockDim.x >> 6) + (threadIdx.x >> 6);
    const int nwaves = gridDim.x * (blockDim.x >> 6);
    for (int e = wave; e < n_edges; e += nwaves) {
        int   col = ecol[e];
        int   row = erow[e];
        float w   = ew[e];
        float2 s  = *(((const float2*)(S + (size_t)col * D)) + lane);
        float* op = out + (size_t)row * D + lane * 2;
        unsafeAtomicAdd(op,     w * s.x);
        unsafeAtomicAdd(op + 1, w * s.y);
    }
}

extern "C" void kernel_launch(void* const* d_in, const int* in_sizes, int n_in,
                              void* d_out, int out_size, void* d_ws, size_t ws_size,
                              hipStream_t stream) {
    const float* X    = (const float*)d_in[0];
    const int*   erow = (const int*)  d_in[1];
    const int*   ecol = (const int*)  d_in[2];
    const float* ew   = (const float*)d_in[3];
    const float* W    = (const float*)d_in[4];
    const float* bias = (const float*)d_in[5];
    float* out = (float*)d_out;

    const int n_nodes = in_sizes[0] / D;
    const int n_edges = in_sizes[1];
    const int nb      = (n_nodes + BROWS - 1) / BROWS;   // 782

    // workspace layout: Sb (bf16) | cnt | cur | binned
    size_t sb_bytes   = (size_t)n_nodes * D * sizeof(unsigned short); // 25.6 MB
    size_t cnt_bytes  = ((size_t)nb * sizeof(int) + 15) & ~(size_t)15;
    size_t sort_bytes = (size_t)n_edges * sizeof(int2);               // 25.6 MB
    size_t need = sb_bytes + 2 * cnt_bytes + sort_bytes + 64;

    if (ws_size >= need && nb <= 1024) {
        char* p = (char*)d_ws;
        unsigned short* Sb = (unsigned short*)p;  p += sb_bytes;
        int* cnt = (int*)p;                       p += cnt_bytes;
        int* cur = (int*)p;                       p += cnt_bytes;
        p = (char*)(((uintptr_t)p + 15) & ~(uintptr_t)15);
        int2* binned = (int2*)p;

        gemm_kernel<true><<<(n_nodes + GEMM_ROWS - 1) / GEMM_ROWS, 256, 0, stream>>>(
            X, W, (void*)Sb, n_nodes);
        hipMemsetAsync(cnt, 0, (size_t)nb * sizeof(int), stream);
        bhist_kernel<<<256, 256, 0, stream>>>(erow, cnt, n_edges, nb);
        bscan_kernel<<<1, 1024, 0, stream>>>(cnt, cur, nb);
        bin_kernel<<<(n_edges + BIN_CHUNK - 1) / BIN_CHUNK, 256, 0, stream>>>(
            erow, ecol, ew, cur, binned, n_edges, nb);
        spmm_bucket_kernel<<<nb, 512, 0, stream>>>(Sb, cur, binned, bias, out, n_nodes);
    } else {
        // fallback: fp32 S + hardware atomics
        float* S = (float*)d_ws;
        gemm_kernel<false><<<(n_nodes + GEMM_ROWS - 1) / GEMM_ROWS, 256, 0, stream>>>(
            X, W, (void*)S, n_nodes);
        init_out_kernel<<<2048, 256, 0, stream>>>(out, bias, n_nodes * (D / 4));
        spmm_atomic_kernel<<<2048, 256, 0, stream>>>(S, erow, ecol, ew, out, n_edges);
    }
}

// Round 6
// 308.447 us; speedup vs baseline: 9.1377x; 9.1377x over previous
//
#include <hip/hip_runtime.h>
#include <hip/hip_bf16.h>

#define D 128          // D_IN == D_OUT == 128
#define GEMM_ROWS 64   // rows per block in the dense GEMM
#define BROWS 128      // nodes per coarse bucket
#define BSHIFT 7       // log2(BROWS)
#define BIN_CHUNK 8192 // edges per binning block
#define SORT_CAP 6144  // max edges sorted in LDS (mean ~4092, sigma ~64)

static __device__ inline unsigned short f2bf(float x) {
    unsigned int u = __float_as_uint(x);
    return (unsigned short)((u + 0x7FFFu + ((u >> 16) & 1u)) >> 16);  // RNE
}
static __device__ inline float bf2f(unsigned int h16) {
    return __uint_as_float(h16 << 16);
}

// ---------------------------------------------------------------------------
// S = X @ W  (fp32 vector GEMM; no fp32 MFMA on CDNA4). Output fp32 or bf16.
// W (64KB) + 64-row X tile (stride 132) in LDS; 4x8 register tile per thread.
// ---------------------------------------------------------------------------
template <bool BF16OUT>
__global__ __launch_bounds__(256) void gemm_kernel(const float* __restrict__ X,
                                                   const float* __restrict__ W,
                                                   void* __restrict__ Sout,
                                                   int n_rows) {
    __shared__ float Ws[D * D];
    __shared__ float Xs[GEMM_ROWS * 132];

    const int tid  = threadIdx.x;
    const int row0 = blockIdx.x * GEMM_ROWS;

    #pragma unroll
    for (int i = 0; i < 16; ++i) {
        int idx = tid + i * 256;
        ((float4*)Ws)[idx] = ((const float4*)W)[idx];
    }
    #pragma unroll
    for (int i = 0; i < 8; ++i) {
        int idx = tid + i * 256;
        int r = idx >> 5, c4 = idx & 31;
        if (row0 + r < n_rows) {
            float4 v = ((const float4*)(X + (size_t)(row0 + r) * D))[c4];
            *((float4*)&Xs[r * 132 + c4 * 4]) = v;
        }
    }
    __syncthreads();

    const int cg = tid & 15, rg = tid >> 4;
    const int r0 = rg * 4;
    const int c0 = cg * 4;
    const int c1 = 64 + cg * 4;

    float acc[4][8];
    #pragma unroll
    for (int r = 0; r < 4; ++r)
        #pragma unroll
        for (int c = 0; c < 8; ++c) acc[r][c] = 0.f;

    #pragma unroll 4
    for (int k = 0; k < D; ++k) {
        float4 w0 = *((const float4*)&Ws[k * D + c0]);
        float4 w1 = *((const float4*)&Ws[k * D + c1]);
        #pragma unroll
        for (int r = 0; r < 4; ++r) {
            float x = Xs[(r0 + r) * 132 + k];
            acc[r][0] += x * w0.x; acc[r][1] += x * w0.y;
            acc[r][2] += x * w0.z; acc[r][3] += x * w0.w;
            acc[r][4] += x * w1.x; acc[r][5] += x * w1.y;
            acc[r][6] += x * w1.z; acc[r][7] += x * w1.w;
        }
    }

    #pragma unroll
    for (int r = 0; r < 4; ++r) {
        int row = row0 + r0 + r;
        if (row < n_rows) {
            if constexpr (BF16OUT) {
                unsigned short* Sb = (unsigned short*)Sout;
                uint2 v0, v1;
                v0.x = (unsigned)f2bf(acc[r][0]) | ((unsigned)f2bf(acc[r][1]) << 16);
                v0.y = (unsigned)f2bf(acc[r][2]) | ((unsigned)f2bf(acc[r][3]) << 16);
                v1.x = (unsigned)f2bf(acc[r][4]) | ((unsigned)f2bf(acc[r][5]) << 16);
                v1.y = (unsigned)f2bf(acc[r][6]) | ((unsigned)f2bf(acc[r][7]) << 16);
                ((uint2*)(Sb + (size_t)row * D))[cg]      = v0;
                ((uint2*)(Sb + (size_t)row * D))[16 + cg] = v1;
            } else {
                float* S = (float*)Sout;
                float4 o0 = {acc[r][0], acc[r][1], acc[r][2], acc[r][3]};
                float4 o1 = {acc[r][4], acc[r][5], acc[r][6], acc[r][7]};
                ((float4*)(S + (size_t)row * D))[cg]      = o0;
                ((float4*)(S + (size_t)row * D))[16 + cg] = o1;
            }
        }
    }
}

// ---------------------------------------------------------------------------
// Coarse bucket histogram: LDS-aggregated, one global atomic per bucket/block.
// ---------------------------------------------------------------------------
__global__ __launch_bounds__(256) void bhist_kernel(const int* __restrict__ erow,
                                                    int* __restrict__ cnt,
                                                    int n_edges, int nb) {
    __shared__ int h[1024];
    for (int i = threadIdx.x; i < nb; i += 256) h[i] = 0;
    __syncthreads();
    int i = blockIdx.x * blockDim.x + threadIdx.x;
    int stride = gridDim.x * blockDim.x;
    for (; i < n_edges; i += stride) atomicAdd(&h[erow[i] >> BSHIFT], 1);
    __syncthreads();
    for (int b = threadIdx.x; b < nb; b += 256)
        if (h[b]) atomicAdd(&cnt[b], h[b]);
}

// single block: exclusive scan of cnt -> bstart (stable) and curm (cursors)
__global__ __launch_bounds__(1024) void bscan_kernel(const int* __restrict__ cnt,
                                                     int* __restrict__ bstart,
                                                     int* __restrict__ curm, int nb) {
    __shared__ int s[1024];
    int tid = threadIdx.x;
    int v = (tid < nb) ? cnt[tid] : 0;
    s[tid] = v;
    __syncthreads();
    for (int d = 1; d < 1024; d <<= 1) {
        int t = (tid >= d) ? s[tid - d] : 0;
        __syncthreads();
        s[tid] += t;
        __syncthreads();
    }
    if (tid < nb) {
        int e = s[tid] - v;   // exclusive
        bstart[tid] = e;
        curm[tid]   = e;
    }
}

// ---------------------------------------------------------------------------
// Binning: each block takes BIN_CHUNK edges, reserves one contiguous range per
// touched bucket (1 global atomic per (block,bucket)), writes densely into it.
// Packed edge: x = (localrow<<25) | col, y = weight bits.
// ---------------------------------------------------------------------------
__global__ __launch_bounds__(256) void bin_kernel(const int* __restrict__ erow,
                                                  const int* __restrict__ ecol,
                                                  const float* __restrict__ ew,
                                                  int* __restrict__ curm,
                                                  int2* __restrict__ binned,
                                                  int n_edges, int nb) {
    __shared__ int h[1024];
    __shared__ int base[1024];
    const int c0 = blockIdx.x * BIN_CHUNK;
    for (int i = threadIdx.x; i < nb; i += 256) h[i] = 0;
    __syncthreads();
    for (int k = 0; k < BIN_CHUNK; k += 256) {
        int e = c0 + k + threadIdx.x;
        if (e < n_edges) atomicAdd(&h[erow[e] >> BSHIFT], 1);
    }
    __syncthreads();
    for (int b = threadIdx.x; b < nb; b += 256) {
        int c = h[b];
        if (c) base[b] = atomicAdd(&curm[b], c);
        h[b] = 0;   // reuse as local cursor
    }
    __syncthreads();
    for (int k = 0; k < BIN_CHUNK; k += 256) {
        int e = c0 + k + threadIdx.x;
        if (e < n_edges) {
            int row = erow[e];
            int b = row >> BSHIFT;
            int pos = base[b] + atomicAdd(&h[b], 1);
            int2 p;
            p.x = (int)(((unsigned)(row & (BROWS - 1)) << 25) | (unsigned)ecol[e]);
            p.y = __float_as_int(ew[e]);
            binned[pos] = p;
        }
    }
}

// ---------------------------------------------------------------------------
// Per-bucket counting sort by local row, IN PLACE in `binned` (LDS staging,
// linear coalesced write-back). Also emits per-node CSR start offsets.
// Overflow (>SORT_CAP, unreachable for this data) bounces via aux (= d_out,
// free until spmm runs; per-bucket ranges are disjoint).
// ---------------------------------------------------------------------------
__global__ __launch_bounds__(256) void csr_sort_kernel(const int* __restrict__ cnt,
                                                       const int* __restrict__ bstart,
                                                       int2* __restrict__ binned,
                                                       int2* __restrict__ aux,
                                                       int* __restrict__ offs,
                                                       int n_nodes) {
    __shared__ int  lhist[BROWS];
    __shared__ int  lscan[BROWS];
    __shared__ int  lcur[BROWS];
    __shared__ int2 staged[SORT_CAP];   // 48 KB

    const int b    = blockIdx.x;
    const int bs   = bstart[b];
    const int cb   = cnt[b];
    const int row0 = b * BROWS;
    const int tid  = threadIdx.x;

    if (tid < BROWS) lhist[tid] = 0;
    __syncthreads();

    for (int i = tid; i < cb; i += 256)
        atomicAdd(&lhist[(unsigned)binned[bs + i].x >> 25], 1);
    __syncthreads();

    // inclusive Hillis-Steele scan over 128 bins
    if (tid < BROWS) lscan[tid] = lhist[tid];
    __syncthreads();
    for (int d = 1; d < BROWS; d <<= 1) {
        int t = 0;
        if (tid < BROWS && tid >= d) t = lscan[tid - d];
        __syncthreads();
        if (tid < BROWS) lscan[tid] += t;
        __syncthreads();
    }
    if (tid < BROWS) {
        int excl = lscan[tid] - lhist[tid];
        lcur[tid] = excl;
        if (row0 + tid < n_nodes) offs[row0 + tid] = bs + excl;
    }
    __syncthreads();

    if (cb <= SORT_CAP) {
        for (int i = tid; i < cb; i += 256) {
            int2 p = binned[bs + i];
            int pos = atomicAdd(&lcur[(unsigned)p.x >> 25], 1);
            int2 q; q.x = p.x & 0x1FFFFFF; q.y = p.y;
            staged[pos] = q;
        }
        __syncthreads();
        for (int i = tid; i < cb; i += 256)
            binned[bs + i] = staged[i];
    } else {
        for (int i = tid; i < cb; i += 256) aux[bs + i] = binned[bs + i];
        __syncthreads();
        for (int i = tid; i < cb; i += 256) {
            int2 p = aux[bs + i];
            int pos = atomicAdd(&lcur[(unsigned)p.x >> 25], 1);
            int2 q; q.x = p.x & 0x1FFFFFF; q.y = p.y;
            binned[bs + pos] = q;
        }
    }
}

// ---------------------------------------------------------------------------
// CSR SpMM: one wave per node. Lane l owns cols 2l,2l+1; bf16 S gather is
// 4 B/lane (256 B/row, coalesced). Register accumulation, bias fused,
// single coalesced write, no atomics. 4-edge unroll for MLP.
// ---------------------------------------------------------------------------
__global__ __launch_bounds__(256) void spmm_csr_kernel(const unsigned short* __restrict__ Sb,
                                                       const int* __restrict__ offs,
                                                       const int2* __restrict__ edges,
                                                       const float* __restrict__ bias,
                                                       float* __restrict__ out,
                                                       int n_nodes, int n_edges) {
    int node = blockIdx.x * 4 + (threadIdx.x >> 6);
    int lane = threadIdx.x & 63;
    if (node >= n_nodes) return;
    int start = offs[node];
    int end   = (node + 1 < n_nodes) ? offs[node + 1] : n_edges;

    float2 b2 = ((const float2*)bias)[lane];
    float ax = b2.x, ay = b2.y;

    int e = start;
    for (; e + 3 < end; e += 4) {
        int2 p0 = edges[e], p1 = edges[e + 1], p2 = edges[e + 2], p3 = edges[e + 3];
        unsigned s0 = ((const unsigned*)(Sb + (size_t)p0.x * D))[lane];
        unsigned s1 = ((const unsigned*)(Sb + (size_t)p1.x * D))[lane];
        unsigned s2 = ((const unsigned*)(Sb + (size_t)p2.x * D))[lane];
        unsigned s3 = ((const unsigned*)(Sb + (size_t)p3.x * D))[lane];
        float w0 = __int_as_float(p0.y), w1 = __int_as_float(p1.y);
        float w2 = __int_as_float(p2.y), w3 = __int_as_float(p3.y);
        ax += w0 * bf2f(s0 & 0xFFFFu) + w1 * bf2f(s1 & 0xFFFFu)
            + w2 * bf2f(s2 & 0xFFFFu) + w3 * bf2f(s3 & 0xFFFFu);
        ay += w0 * bf2f(s0 >> 16) + w1 * bf2f(s1 >> 16)
            + w2 * bf2f(s2 >> 16) + w3 * bf2f(s3 >> 16);
    }
    for (; e < end; ++e) {
        int2 p = edges[e];
        unsigned s = ((const unsigned*)(Sb + (size_t)p.x * D))[lane];
        float w = __int_as_float(p.y);
        ax += w * bf2f(s & 0xFFFFu);
        ay += w * bf2f(s >> 16);
    }

    float2 o; o.x = ax; o.y = ay;
    ((float2*)(out + (size_t)node * D))[lane] = o;
}

// ---------------------------------------------------------------------------
// Fallback path (ws too small / too many buckets): fp32 S + output atomics.
// ---------------------------------------------------------------------------
__global__ __launch_bounds__(256) void init_out_kernel(float* __restrict__ out,
                                                       const float* __restrict__ bias,
                                                       int total4) {
    int idx = blockIdx.x * blockDim.x + threadIdx.x;
    int stride = gridDim.x * blockDim.x;
    for (; idx < total4; idx += stride) {
        float4 b = ((const float4*)bias)[idx & 31];
        ((float4*)out)[idx] = b;
    }
}

__global__ __launch_bounds__(256) void spmm_atomic_kernel(const float* __restrict__ S,
                                                          const int* __restrict__ erow,
                                                          const int* __restrict__ ecol,
                                                          const float* __restrict__ ew,
                                                          float* __restrict__ out,
                                                          int n_edges) {
    const int lane   = threadIdx.x & 63;
    const int wave   = blockIdx.x * (blockDim.x >> 6) + (threadIdx.x >> 6);
    const int nwaves = gridDim.x * (blockDim.x >> 6);
    for (int e = wave; e < n_edges; e += nwaves) {
        int   col = ecol[e];
        int   row = erow[e];
        float w   = ew[e];
        float2 s  = *(((const float2*)(S + (size_t)col * D)) + lane);
        float* op = out + (size_t)row * D + lane * 2;
        unsafeAtomicAdd(op,     w * s.x);
        unsafeAtomicAdd(op + 1, w * s.y);
    }
}

extern "C" void kernel_launch(void* const* d_in, const int* in_sizes, int n_in,
                              void* d_out, int out_size, void* d_ws, size_t ws_size,
                              hipStream_t stream) {
    const float* X    = (const float*)d_in[0];
    const int*   erow = (const int*)  d_in[1];
    const int*   ecol = (const int*)  d_in[2];
    const float* ew   = (const float*)d_in[3];
    const float* W    = (const float*)d_in[4];
    const float* bias = (const float*)d_in[5];
    float* out = (float*)d_out;

    const int n_nodes = in_sizes[0] / D;
    const int n_edges = in_sizes[1];
    const int nb      = (n_nodes + BROWS - 1) / BROWS;   // 782

    // workspace: Sb (bf16) | cnt | bstart | curm | offs | binned
    size_t sb_bytes   = (size_t)n_nodes * D * sizeof(unsigned short); // 25.6 MB
    size_t cnt_bytes  = ((size_t)nb * sizeof(int) + 15) & ~(size_t)15;
    size_t offs_bytes = ((size_t)n_nodes * sizeof(int) + 15) & ~(size_t)15;
    size_t bin_bytes  = (size_t)n_edges * sizeof(int2);               // 25.6 MB
    size_t need = sb_bytes + 3 * cnt_bytes + offs_bytes + bin_bytes + 64;
    // aux for (unreachable) sort overflow = d_out, free until spmm writes it
    bool aux_ok = (size_t)out_size * sizeof(float) >= bin_bytes;

    if (ws_size >= need && nb <= 1024 && aux_ok) {
        char* p = (char*)d_ws;
        unsigned short* Sb = (unsigned short*)p;  p += sb_bytes;
        int* cnt    = (int*)p;                    p += cnt_bytes;
        int* bstart = (int*)p;                    p += cnt_bytes;
        int* curm   = (int*)p;                    p += cnt_bytes;
        int* offs   = (int*)p;                    p += offs_bytes;
        p = (char*)(((uintptr_t)p + 15) & ~(uintptr_t)15);
        int2* binned = (int2*)p;

        gemm_kernel<true><<<(n_nodes + GEMM_ROWS - 1) / GEMM_ROWS, 256, 0, stream>>>(
            X, W, (void*)Sb, n_nodes);
        hipMemsetAsync(cnt, 0, (size_t)nb * sizeof(int), stream);
        bhist_kernel<<<256, 256, 0, stream>>>(erow, cnt, n_edges, nb);
        bscan_kernel<<<1, 1024, 0, stream>>>(cnt, bstart, curm, nb);
        bin_kernel<<<(n_edges + BIN_CHUNK - 1) / BIN_CHUNK, 256, 0, stream>>>(
            erow, ecol, ew, curm, binned, n_edges, nb);
        csr_sort_kernel<<<nb, 256, 0, stream>>>(cnt, bstart, binned, (int2*)out,
                                                offs, n_nodes);
        spmm_csr_kernel<<<(n_nodes + 3) / 4, 256, 0, stream>>>(Sb, offs, binned, bias,
                                                               out, n_nodes, n_edges);
    } else {
        float* S = (float*)d_ws;
        gemm_kernel<false><<<(n_nodes + GEMM_ROWS - 1) / GEMM_ROWS, 256, 0, stream>>>(
            X, W, (void*)S, n_nodes);
        init_out_kernel<<<2048, 256, 0, stream>>>(out, bias, n_nodes * (D / 4));
        spmm_atomic_kernel<<<2048, 256, 0, stream>>>(S, erow, ecol, ew, out, n_edges);
    }
}